// Round 6
// baseline (355.966 us; speedup 1.0000x reference)
//
#include <hip/hip_runtime.h>
#include <stdint.h>

typedef unsigned long long u64;

#define PADW 134
#define WPR 3                        // 3 u64 words per 134-voxel row
#define ROWS_PER_B (PADW * PADW)     // 17,956 rows per batch
#define WPB (ROWS_PER_B * WPR)       // 53,868 words per batch
#define NBATCH 2
#define NROWS (NBATCH * ROWS_PER_B)  // 35,912
#define NWORDS (NBATCH * WPB)        // 107,736
#define NV 128
#define NV3 (NV * NV * NV)
#define PAD 3

// Bit i of word j in row (z,y) = voxel x = j*64+i. Invariant: all STORED buffers
// (X, E*, sk*) have invalid bits (word 2 bits 6..63) == 0.

__device__ __forceinline__ bool inR(int v) { return (unsigned)v < (unsigned)PADW; }

__device__ __forceinline__ void loadRow(const u64* __restrict__ B, int z, int y, u64 r[3]) {
  const u64* p = B + (z * PADW + y) * WPR;
  r[0] = p[0]; r[1] = p[1]; r[2] = p[2];
}

// d |= horizontal 3-dilation of row r (OOB x -> 0, OR identity)
__device__ __forceinline__ void orHdil(const u64 r[3], u64 d[3]) {
  d[0] |= r[0] | (r[0] << 1) | ((r[0] >> 1) | (r[1] << 63));
  d[1] |= r[1] | ((r[1] << 1) | (r[0] >> 63)) | ((r[1] >> 1) | (r[2] << 63));
  d[2] |= r[2] | ((r[2] << 1) | (r[1] >> 63)) | (r[2] >> 1);
}

// e = horizontal 3-erosion of row c (OOB x -> 1, AND identity).
// e inherits c's zero invalid bits.
__device__ __forceinline__ void eroX(const u64 c[3], u64 e[3]) {
  e[0] = c[0] & ((c[0] << 1) | 1ULL)        & ((c[0] >> 1) | (c[1] << 63));
  e[1] = c[1] & ((c[1] << 1) | (c[0] >> 63)) & ((c[1] >> 1) | (c[2] << 63));
  e[2] = c[2] & ((c[2] << 1) | (c[1] >> 63)) & ((c[2] >> 1) | (1ULL << 5));
}

__device__ __forceinline__ void ridDecomp(int rid, int& b, int& z, int& y) {
  b = rid / ROWS_PER_B;
  int r = rid - b * ROWS_PER_B;
  z = r / PADW;
  y = r - z * PADW;
}

// ---------------------------------------------------------------- binarize + pad + pack
// Also zeroes the reduction accumulators/counter (ws is re-poisoned before every call).
__global__ void binpack_k(const float* __restrict__ logit, u64* __restrict__ X,
                          double* __restrict__ acc, unsigned* __restrict__ cnt) {
  if (blockIdx.x == 0 && threadIdx.x == 0) {
#pragma unroll
    for (int k = 0; k < 8; ++k) acc[k] = 0.0;
    *cnt = 0u;
  }
  int wid = (blockIdx.x * blockDim.x + threadIdx.x) >> 6;
  int lane = threadIdx.x & 63;
  if (wid >= NROWS) return;
  int b, z, y;
  ridDecomp(wid, b, z, y);
  bool padrow = (z < PAD || z >= PAD + NV || y < PAD || y >= PAD + NV);
  const float TH = 0.84729786f;  // ln(0.7/0.3): sigmoid(l)>0.7 <=> l>TH
  u64* rowp = X + (size_t)b * WPB + (z * PADW + y) * WPR;
#pragma unroll
  for (int j = 0; j < WPR; ++j) {
    int x = j * 64 + lane;
    bool pred = false;
    if (x < PADW) {
      if (padrow || x < PAD || x >= PAD + NV) {
        pred = true;  // pad voxel = 1
      } else {
        float l = logit[(((size_t)b * NV + (z - PAD)) * NV + (y - PAD)) * NV + (x - PAD)];
        pred = l > TH;
      }
    }
    u64 w = __ballot(pred);
    if (lane == 0) rowp[j] = w;
  }
}

// ---------------------------------------------------------------- E = ero6(B), thread per row
__global__ void ero_k(const u64* __restrict__ in, u64* __restrict__ out) {
  int rid = blockIdx.x * blockDim.x + threadIdx.x;
  if (rid >= NROWS) return;
  int b, z, y;
  ridDecomp(rid, b, z, y);
  const u64* Bb = in + (size_t)b * WPB;
  u64 c[3], e[3], n[3];
  loadRow(Bb, z, y, c);
  eroX(c, e);
  if (inR(y - 1)) { loadRow(Bb, z, y - 1, n); e[0] &= n[0]; e[1] &= n[1]; e[2] &= n[2]; }
  if (inR(y + 1)) { loadRow(Bb, z, y + 1, n); e[0] &= n[0]; e[1] &= n[1]; e[2] &= n[2]; }
  if (inR(z - 1)) { loadRow(Bb, z - 1, y, n); e[0] &= n[0]; e[1] &= n[1]; e[2] &= n[2]; }
  if (inR(z + 1)) { loadRow(Bb, z + 1, y, n); e[0] &= n[0]; e[1] &= n[1]; e[2] &= n[2]; }
  u64* o = out + (size_t)b * WPB + (z * PADW + y) * WPR;
  o[0] = e[0]; o[1] = e[1]; o[2] = e[2];
}

// ---------------------------------------------------------------- init:
// sk = X & ~dil26(E1);  E2 = ero6(E1)   (cross rows reused from the dilation's 3x3)
__global__ void open_init2_k(const u64* __restrict__ X, const u64* __restrict__ E1,
                             u64* __restrict__ sk, u64* __restrict__ E2) {
  int rid = blockIdx.x * blockDim.x + threadIdx.x;
  if (rid >= NROWS) return;
  int b, z, y;
  ridDecomp(rid, b, z, y);
  size_t boff = (size_t)b * WPB;
  const u64* Eb = E1 + boff;
  u64 acc[3] = {0, 0, 0};
  u64 cc[3];
  u64 cy0[3] = {~0ULL, ~0ULL, ~0ULL}, cy1[3] = {~0ULL, ~0ULL, ~0ULL};
  u64 cz0[3] = {~0ULL, ~0ULL, ~0ULL}, cz1[3] = {~0ULL, ~0ULL, ~0ULL};
#pragma unroll
  for (int dz = -1; dz <= 1; ++dz) {
#pragma unroll
    for (int dy = -1; dy <= 1; ++dy) {
      int zz = z + dz, yy = y + dy;
      if (!inR(zz) || !inR(yy)) continue;  // OR identity
      u64 t[3];
      loadRow(Eb, zz, yy, t);
      orHdil(t, acc);
      if (dz == 0 && dy == 0) { cc[0] = t[0]; cc[1] = t[1]; cc[2] = t[2]; }
      else if (dz == 0 && dy == -1) { cy0[0] = t[0]; cy0[1] = t[1]; cy0[2] = t[2]; }
      else if (dz == 0 && dy == 1)  { cy1[0] = t[0]; cy1[1] = t[1]; cy1[2] = t[2]; }
      else if (dz == -1 && dy == 0) { cz0[0] = t[0]; cz0[1] = t[1]; cz0[2] = t[2]; }
      else if (dz == 1 && dy == 0)  { cz1[0] = t[0]; cz1[1] = t[1]; cz1[2] = t[2]; }
    }
  }
  u64 xr[3];
  loadRow(X + boff, z, y, xr);
  u64 e[3];
  eroX(cc, e);
#pragma unroll
  for (int j = 0; j < 3; ++j) e[j] &= cy0[j] & cy1[j] & cz0[j] & cz1[j];
  int rw = (z * PADW + y) * WPR;
#pragma unroll
  for (int j = 0; j < 3; ++j) {
    sk[boff + rw + j] = xr[j] & ~acc[j];  // acc junk bits killed by clean xr
    E2[boff + rw + j] = e[j];
  }
}

// ---------------------------------------------------------------- fused iteration:
// delta = E1 & ~dil26(E2); sk2 = delta | sk | (X & dil26(sk)); E3 = ero6(E2)
__global__ void update2_k(const u64* __restrict__ X, const u64* __restrict__ E1,
                          const u64* __restrict__ E2, const u64* __restrict__ sk,
                          u64* __restrict__ sk2, u64* __restrict__ E3) {
  int rid = blockIdx.x * blockDim.x + threadIdx.x;
  if (rid >= NROWS) return;
  int b, z, y;
  ridDecomp(rid, b, z, y);
  size_t boff = (size_t)b * WPB;
  const u64* Eb = E2 + boff;
  const u64* Sb = sk + boff;
  u64 acc[3] = {0, 0, 0}, dsk[3] = {0, 0, 0};
  u64 cc[3], skc[3];
  u64 cy0[3] = {~0ULL, ~0ULL, ~0ULL}, cy1[3] = {~0ULL, ~0ULL, ~0ULL};
  u64 cz0[3] = {~0ULL, ~0ULL, ~0ULL}, cz1[3] = {~0ULL, ~0ULL, ~0ULL};
#pragma unroll
  for (int dz = -1; dz <= 1; ++dz) {
#pragma unroll
    for (int dy = -1; dy <= 1; ++dy) {
      int zz = z + dz, yy = y + dy;
      if (!inR(zz) || !inR(yy)) continue;
      u64 t[3], s[3];
      loadRow(Eb, zz, yy, t);
      loadRow(Sb, zz, yy, s);
      orHdil(t, acc);
      orHdil(s, dsk);
      if (dz == 0 && dy == 0) {
        cc[0] = t[0]; cc[1] = t[1]; cc[2] = t[2];
        skc[0] = s[0]; skc[1] = s[1]; skc[2] = s[2];
      }
      else if (dz == 0 && dy == -1) { cy0[0] = t[0]; cy0[1] = t[1]; cy0[2] = t[2]; }
      else if (dz == 0 && dy == 1)  { cy1[0] = t[0]; cy1[1] = t[1]; cy1[2] = t[2]; }
      else if (dz == -1 && dy == 0) { cz0[0] = t[0]; cz0[1] = t[1]; cz0[2] = t[2]; }
      else if (dz == 1 && dy == 0)  { cz1[0] = t[0]; cz1[1] = t[1]; cz1[2] = t[2]; }
    }
  }
  u64 e1r[3], xr[3];
  loadRow(E1 + boff, z, y, e1r);
  loadRow(X + boff, z, y, xr);
  u64 e[3];
  eroX(cc, e);
#pragma unroll
  for (int j = 0; j < 3; ++j) e[j] &= cy0[j] & cy1[j] & cz0[j] & cz1[j];
  int rw = (z * PADW + y) * WPR;
#pragma unroll
  for (int j = 0; j < 3; ++j) {
    u64 delta = e1r[j] & ~acc[j];          // clean: e1r clean
    u64 s1 = (xr[j] & dsk[j]) | skc[j];    // clean: xr, skc clean
    sk2[boff + rw + j] = delta | s1;
    E3[boff + rw + j] = e[j];
  }
}

// ---------------------------------------------------------------- reduction (+fused finalize)
// 2048 blocks x 256 threads: thread t handles float4 #t of each batch (exactly NV3/4 = 524288).
__global__ __launch_bounds__(256, 8) void reduce_k(const float* __restrict__ logit,
                                                   const float* __restrict__ vcl,
                                                   const u64* __restrict__ S,
                                                   double* __restrict__ acc,
                                                   unsigned* __restrict__ cnt,
                                                   float* __restrict__ out) {
  int t = blockIdx.x * 256 + threadIdx.x;  // [0, 524288)
  int i = t << 2;
  int z = i >> 14, y = (i >> 7) & 127, x = i & 127;
  float p[8];
#pragma unroll
  for (int k = 0; k < 8; ++k) p[k] = 0.f;
#pragma unroll
  for (int b = 0; b < NBATCH; ++b) {
    float4 lv = ((const float4*)(logit + (size_t)b * NV3))[t];
    float4 cv = ((const float4*)(vcl + (size_t)b * NV3))[t];
    const u64* rowp = S + (size_t)b * WPB + ((size_t)(z + PAD) * PADW + (y + PAD)) * WPR;
    float lf[4] = {lv.x, lv.y, lv.z, lv.w};
    float cf[4] = {cv.x, cv.y, cv.z, cv.w};
#pragma unroll
    for (int k = 0; k < 4; ++k) {
      float vp = 1.0f / (1.0f + expf(-lf[k]));
      int xp = x + k + PAD;
      u64 w = rowp[xp >> 6];
      float s = (float)((w >> (xp & 63)) & 1ULL);
      float c = cf[k];
      p[b * 4 + 0] += vp * c;
      p[b * 4 + 1] += c;
      p[b * 4 + 2] += c * vp * s;
      p[b * 4 + 3] += vp * s;
    }
  }
  // wave reduce (64-wide)
#pragma unroll
  for (int k = 0; k < 8; ++k)
    for (int off = 32; off > 0; off >>= 1) p[k] += __shfl_down(p[k], off);
  __shared__ float ls[4][8];
  int wid = threadIdx.x >> 6, lane = threadIdx.x & 63;
  if (lane == 0) {
#pragma unroll
    for (int k = 0; k < 8; ++k) ls[wid][k] = p[k];
  }
  __syncthreads();
  if (threadIdx.x == 0) {
#pragma unroll
    for (int k = 0; k < 8; ++k) {
      double a = (double)ls[0][k] + ls[1][k] + ls[2][k] + ls[3][k];
      atomicAdd(&acc[k], a);
    }
    __threadfence();
    unsigned old = atomicAdd(cnt, 1u);
    if (old == gridDim.x - 1) {  // last block: finalize
      __threadfence();
      double a[8];
#pragma unroll
      for (int k = 0; k < 8; ++k) a[k] = atomicAdd(&acc[k], 0.0);  // coherent read
      const double eps = 1e-12;
      double tp = 0.5 * ((a[0] + eps) / (a[1] + eps) + (a[4] + eps) / (a[5] + eps));
      double ts = 0.5 * ((a[2] + eps) / (a[3] + eps) + (a[6] + eps) / (a[7] + eps));
      out[0] = (float)(1.0 - (2.0 * tp * ts + eps) / (tp + ts + eps));
    }
  }
}

// ---------------------------------------------------------------- host side
extern "C" void kernel_launch(void* const* d_in, const int* in_sizes, int n_in,
                              void* d_out, int out_size, void* d_ws, size_t ws_size,
                              hipStream_t stream) {
  const float* logit = (const float*)d_in[0];  // Vlogit
  const float* vcl = (const float*)d_in[1];    // Vcl
  // d_in[2] (Vedt) unused by the reference loss
  float* out = (float*)d_out;

  const size_t bufW = (size_t)NWORDS;
  u64* base = (u64*)d_ws;
  u64* B[7];
  for (int i = 0; i < 7; ++i) B[i] = base + (size_t)i * bufW;
  double* acc = (double*)(base + 7 * bufW);
  unsigned* cnt = (unsigned*)(acc + 8);

  const int mThreads = 64;
  const int mBlocks = (NROWS + mThreads - 1) / mThreads;  // 562
  const int bBlocks = (NROWS + 3) / 4;                    // binpack: 4 waves/block

  binpack_k<<<bBlocks, 256, 0, stream>>>(logit, B[0], acc, cnt);

  // ---- skeletonize #1 (5 iters)
  u64 *X = B[0], *E1 = B[1], *E2 = B[2], *E3 = B[3], *sk = B[4], *sk2 = B[5];
  ero_k<<<mBlocks, mThreads, 0, stream>>>(X, E1);
  open_init2_k<<<mBlocks, mThreads, 0, stream>>>(X, E1, sk, E2);
  for (int it = 0; it < 5; ++it) {
    update2_k<<<mBlocks, mThreads, 0, stream>>>(X, E1, E2, sk, sk2, E3);
    u64* t = X; X = E1; E1 = E2; E2 = E3; E3 = t;
    t = sk; sk = sk2; sk2 = t;
  }
  u64* S1 = sk;  // binary support == clamped skel

  // ---- skeletonize #2 (2 iters) on S1; B[6] + retired buffers as scratch
  u64 *X2 = S1, *E1b = B[6], *E2b = X, *E3b = E1, *skb = E2, *sk2b = E3;
  ero_k<<<mBlocks, mThreads, 0, stream>>>(X2, E1b);
  open_init2_k<<<mBlocks, mThreads, 0, stream>>>(X2, E1b, skb, E2b);
  for (int it = 0; it < 2; ++it) {
    update2_k<<<mBlocks, mThreads, 0, stream>>>(X2, E1b, E2b, skb, sk2b, E3b);
    u64* t = X2; X2 = E1b; E1b = E2b; E2b = E3b; E3b = t;
    t = skb; skb = sk2b; sk2b = t;
  }
  u64* Sfinal = skb;

  reduce_k<<<524288 / 256, 256, 0, stream>>>(logit, vcl, Sfinal, acc, cnt, out);
}

// Round 7
// 172.556 us; speedup vs baseline: 2.0629x; 2.0629x over previous
//
#include <hip/hip_runtime.h>
#include <stdint.h>

typedef unsigned long long u64;

#define PADW 134
#define WPR 3                        // 3 u64 words per 134-voxel row
#define ROWS_PER_B (PADW * PADW)     // 17,956 rows per batch
#define WPB (ROWS_PER_B * WPR)       // 53,868 words per batch
#define NBATCH 2
#define NROWS (NBATCH * ROWS_PER_B)  // 35,912
#define NWORDS (NBATCH * WPB)        // 107,736
#define NV 128
#define NV3 (NV * NV * NV)
#define PAD 3
#define RBLK 512                     // stage-1 reduction blocks

// Bit i of word j in row (z,y) = voxel x = j*64+i. Invariant: all STORED buffers
// (X, E*, sk*) have invalid bits (word 2 bits 6..63) == 0.

__device__ __forceinline__ bool inR(int v) { return (unsigned)v < (unsigned)PADW; }

// load word j-1, j, j+1 of row (z,y); missing edge words -> 0
__device__ __forceinline__ void load3w(const u64* __restrict__ B, int z, int y, int j,
                                       u64 w[3]) {
  const u64* p = B + (z * PADW + y) * WPR;
  w[0] = j > 0 ? p[j - 1] : 0ULL;
  w[1] = p[j];
  w[2] = j < 2 ? p[j + 1] : 0ULL;
}

// horizontal 3-dilation of word j (OOB x -> 0; zero-filled edge words give that)
__device__ __forceinline__ u64 hdilw(const u64 w[3]) {
  return w[1] | (w[1] << 1) | (w[0] >> 63) | (w[1] >> 1) | (w[2] << 63);
}

// horizontal 3-erosion of word j (OOB x -> 1: x=-1 left of word 0, x=134 right of bit 5 word 2)
__device__ __forceinline__ u64 herow(const u64 w[3], int j) {
  u64 lin = (j == 0) ? 1ULL : (w[0] >> 63);
  u64 rin = (j == 2) ? (1ULL << 5) : (w[2] << 63);
  return w[1] & ((w[1] << 1) | lin) & ((w[1] >> 1) | rin);
}

__device__ __forceinline__ void decompW(int idx, int& b, int& z, int& y, int& j) {
  b = idx / WPB;
  int r = idx - b * WPB;
  z = r / (PADW * WPR);
  int r2 = r - z * (PADW * WPR);
  y = r2 / WPR;
  j = r2 - y * WPR;
}

// ---------------------------------------------------------------- binarize + pad + pack
__global__ void binpack_k(const float* __restrict__ logit, u64* __restrict__ X) {
  int wid = (blockIdx.x * blockDim.x + threadIdx.x) >> 6;
  int lane = threadIdx.x & 63;
  if (wid >= NROWS) return;
  int b = wid / ROWS_PER_B;
  int r = wid - b * ROWS_PER_B;
  int z = r / PADW;
  int y = r - z * PADW;
  bool padrow = (z < PAD || z >= PAD + NV || y < PAD || y >= PAD + NV);
  const float TH = 0.84729786f;  // ln(0.7/0.3): sigmoid(l)>0.7 <=> l>TH
  u64* rowp = X + (size_t)b * WPB + (z * PADW + y) * WPR;
#pragma unroll
  for (int j = 0; j < WPR; ++j) {
    int x = j * 64 + lane;
    bool pred = false;
    if (x < PADW) {
      if (padrow || x < PAD || x >= PAD + NV) {
        pred = true;  // pad voxel = 1
      } else {
        float l = logit[(((size_t)b * NV + (z - PAD)) * NV + (y - PAD)) * NV + (x - PAD)];
        pred = l > TH;
      }
    }
    u64 w = __ballot(pred);
    if (lane == 0) rowp[j] = w;
  }
}

// ---------------------------------------------------------------- E = ero6(B), thread per WORD
__global__ __launch_bounds__(256) void ero_k(const u64* __restrict__ in,
                                             u64* __restrict__ out) {
  int idx = blockIdx.x * blockDim.x + threadIdx.x;
  if (idx >= NWORDS) return;
  int b, z, y, j;
  decompW(idx, b, z, y, j);
  const u64* Bb = in + (size_t)b * WPB;
  u64 c3[3];
  load3w(Bb, z, y, j, c3);
  u64 e = herow(c3, j);
  if (inR(y - 1)) e &= Bb[(z * PADW + y - 1) * WPR + j];
  if (inR(y + 1)) e &= Bb[(z * PADW + y + 1) * WPR + j];
  if (inR(z - 1)) e &= Bb[((z - 1) * PADW + y) * WPR + j];
  if (inR(z + 1)) e &= Bb[((z + 1) * PADW + y) * WPR + j];
  out[idx] = e;
}

// ---------------------------------------------------------------- init, thread per WORD:
// sk = X & ~dil26(E1);  E2 = ero6(E1)
__global__ __launch_bounds__(256) void open_init2_k(const u64* __restrict__ X,
                                                    const u64* __restrict__ E1,
                                                    u64* __restrict__ sk,
                                                    u64* __restrict__ E2) {
  int idx = blockIdx.x * blockDim.x + threadIdx.x;
  if (idx >= NWORDS) return;
  int b, z, y, j;
  decompW(idx, b, z, y, j);
  size_t boff = (size_t)b * WPB;
  const u64* Eb = E1 + boff;
  u64 acc = 0;           // dil26(E1) word
  u64 cc3[3];            // center row 3 words of E1
  u64 ecross = ~0ULL;    // AND of word j over the 4 cross rows
#pragma unroll
  for (int dz = -1; dz <= 1; ++dz) {
#pragma unroll
    for (int dy = -1; dy <= 1; ++dy) {
      int zz = z + dz, yy = y + dy;
      if (!inR(zz) || !inR(yy)) continue;  // dil OR-identity / ero AND-identity
      u64 t3[3];
      load3w(Eb, zz, yy, j, t3);
      acc |= hdilw(t3);
      if (dz == 0 && dy == 0) { cc3[0] = t3[0]; cc3[1] = t3[1]; cc3[2] = t3[2]; }
      else if (dz * dz + dy * dy == 1) ecross &= t3[1];
    }
  }
  u64 e = herow(cc3, j) & ecross;
  u64 xw = X[idx];
  sk[idx] = xw & ~acc;  // acc junk bits killed by clean xw
  E2[idx] = e;
}

// ---------------------------------------------------------------- fused iteration, thread per WORD:
// delta = E1 & ~dil26(E2); sk2 = delta | sk | (X & dil26(sk)); E3 = ero6(E2)
__global__ __launch_bounds__(256) void update2_k(const u64* __restrict__ X,
                                                 const u64* __restrict__ E1,
                                                 const u64* __restrict__ E2,
                                                 const u64* __restrict__ sk,
                                                 u64* __restrict__ sk2,
                                                 u64* __restrict__ E3) {
  int idx = blockIdx.x * blockDim.x + threadIdx.x;
  if (idx >= NWORDS) return;
  int b, z, y, j;
  decompW(idx, b, z, y, j);
  size_t boff = (size_t)b * WPB;
  const u64* Eb = E2 + boff;
  const u64* Sb = sk + boff;
  u64 acc = 0, dsk = 0;
  u64 cc3[3], skcw = 0;
  u64 ecross = ~0ULL;
#pragma unroll
  for (int dz = -1; dz <= 1; ++dz) {
#pragma unroll
    for (int dy = -1; dy <= 1; ++dy) {
      int zz = z + dz, yy = y + dy;
      if (!inR(zz) || !inR(yy)) continue;
      u64 t3[3], s3[3];
      load3w(Eb, zz, yy, j, t3);
      load3w(Sb, zz, yy, j, s3);
      acc |= hdilw(t3);
      dsk |= hdilw(s3);
      if (dz == 0 && dy == 0) {
        cc3[0] = t3[0]; cc3[1] = t3[1]; cc3[2] = t3[2];
        skcw = s3[1];
      } else if (dz * dz + dy * dy == 1) {
        ecross &= t3[1];
      }
    }
  }
  u64 e = herow(cc3, j) & ecross;
  u64 delta = E1[idx] & ~acc;          // clean: E1 clean
  u64 s1 = (X[idx] & dsk) | skcw;      // clean: X, skcw clean
  sk2[idx] = delta | s1;
  E3[idx] = e;
}

// ---------------------------------------------------------------- reduction stage 1
// 512 blocks x 256 threads, grid-stride over 524288 float4 slots; NO atomics:
// block partials -> partials[k*RBLK + blockIdx.x]
__global__ __launch_bounds__(256) void reduce1_k(const float* __restrict__ logit,
                                                 const float* __restrict__ vcl,
                                                 const u64* __restrict__ S,
                                                 float* __restrict__ partials) {
  int tid = blockIdx.x * 256 + threadIdx.x;
  float p[8];
#pragma unroll
  for (int k = 0; k < 8; ++k) p[k] = 0.f;
  for (int s = tid; s < NV3 / 4; s += RBLK * 256) {
    int i = s << 2;
    int z = i >> 14, y = (i >> 7) & 127, x = i & 127;
#pragma unroll
    for (int b = 0; b < NBATCH; ++b) {
      float4 lv = ((const float4*)(logit + (size_t)b * NV3))[s];
      float4 cv = ((const float4*)(vcl + (size_t)b * NV3))[s];
      const u64* rowp = S + (size_t)b * WPB + ((size_t)(z + PAD) * PADW + (y + PAD)) * WPR;
      float lf[4] = {lv.x, lv.y, lv.z, lv.w};
      float cf[4] = {cv.x, cv.y, cv.z, cv.w};
#pragma unroll
      for (int k = 0; k < 4; ++k) {
        float vp = 1.0f / (1.0f + expf(-lf[k]));
        int xp = x + k + PAD;
        u64 w = rowp[xp >> 6];
        float sv = (float)((w >> (xp & 63)) & 1ULL);
        float c = cf[k];
        p[b * 4 + 0] += vp * c;
        p[b * 4 + 1] += c;
        p[b * 4 + 2] += c * vp * sv;
        p[b * 4 + 3] += vp * sv;
      }
    }
  }
#pragma unroll
  for (int k = 0; k < 8; ++k)
    for (int off = 32; off > 0; off >>= 1) p[k] += __shfl_down(p[k], off);
  __shared__ float ls[4][8];
  int wid = threadIdx.x >> 6, lane = threadIdx.x & 63;
  if (lane == 0) {
#pragma unroll
    for (int k = 0; k < 8; ++k) ls[wid][k] = p[k];
  }
  __syncthreads();
  if (threadIdx.x == 0) {
#pragma unroll
    for (int k = 0; k < 8; ++k)
      partials[k * RBLK + blockIdx.x] = ls[0][k] + ls[1][k] + ls[2][k] + ls[3][k];
  }
}

// ---------------------------------------------------------------- reduction stage 2 + loss
__global__ void finalize2_k(const float* __restrict__ partials, float* __restrict__ out) {
  int t = threadIdx.x;  // 512 threads
  double s[8];
#pragma unroll
  for (int k = 0; k < 8; ++k) s[k] = (double)partials[k * RBLK + t];
#pragma unroll
  for (int k = 0; k < 8; ++k)
    for (int off = 32; off > 0; off >>= 1) s[k] += __shfl_down(s[k], off);
  __shared__ double ls[8][8];
  int wid = t >> 6, lane = t & 63;
  if (lane == 0) {
#pragma unroll
    for (int k = 0; k < 8; ++k) ls[k][wid] = s[k];
  }
  __syncthreads();
  if (t == 0) {
    double a[8];
#pragma unroll
    for (int k = 0; k < 8; ++k) {
      a[k] = 0.0;
      for (int w = 0; w < 8; ++w) a[k] += ls[k][w];
    }
    const double eps = 1e-12;
    double tp = 0.5 * ((a[0] + eps) / (a[1] + eps) + (a[4] + eps) / (a[5] + eps));
    double ts = 0.5 * ((a[2] + eps) / (a[3] + eps) + (a[6] + eps) / (a[7] + eps));
    out[0] = (float)(1.0 - (2.0 * tp * ts + eps) / (tp + ts + eps));
  }
}

// ---------------------------------------------------------------- host side
extern "C" void kernel_launch(void* const* d_in, const int* in_sizes, int n_in,
                              void* d_out, int out_size, void* d_ws, size_t ws_size,
                              hipStream_t stream) {
  const float* logit = (const float*)d_in[0];  // Vlogit
  const float* vcl = (const float*)d_in[1];    // Vcl
  // d_in[2] (Vedt) unused by the reference loss
  float* out = (float*)d_out;

  const size_t bufW = (size_t)NWORDS;
  u64* base = (u64*)d_ws;
  u64* B[7];
  for (int i = 0; i < 7; ++i) B[i] = base + (size_t)i * bufW;
  float* partials = (float*)(base + 7 * bufW);  // 8*RBLK floats = 16 KB

  const int mThreads = 256;
  const int mBlocks = (NWORDS + mThreads - 1) / mThreads;  // 421
  const int bBlocks = (NROWS + 3) / 4;                     // binpack: 4 waves/block

  binpack_k<<<bBlocks, 256, 0, stream>>>(logit, B[0]);

  // ---- skeletonize #1 (5 iters)
  u64 *X = B[0], *E1 = B[1], *E2 = B[2], *E3 = B[3], *sk = B[4], *sk2 = B[5];
  ero_k<<<mBlocks, mThreads, 0, stream>>>(X, E1);
  open_init2_k<<<mBlocks, mThreads, 0, stream>>>(X, E1, sk, E2);
  for (int it = 0; it < 5; ++it) {
    update2_k<<<mBlocks, mThreads, 0, stream>>>(X, E1, E2, sk, sk2, E3);
    u64* t = X; X = E1; E1 = E2; E2 = E3; E3 = t;
    t = sk; sk = sk2; sk2 = t;
  }
  u64* S1 = sk;  // binary support == clamped skel

  // ---- skeletonize #2 (2 iters) on S1; B[6] + retired buffers as scratch
  u64 *X2 = S1, *E1b = B[6], *E2b = X, *E3b = E1, *skb = E2, *sk2b = E3;
  ero_k<<<mBlocks, mThreads, 0, stream>>>(X2, E1b);
  open_init2_k<<<mBlocks, mThreads, 0, stream>>>(X2, E1b, skb, E2b);
  for (int it = 0; it < 2; ++it) {
    update2_k<<<mBlocks, mThreads, 0, stream>>>(X2, E1b, E2b, skb, sk2b, E3b);
    u64* t = X2; X2 = E1b; E1b = E2b; E2b = E3b; E3b = t;
    t = skb; skb = sk2b; sk2b = t;
  }
  u64* Sfinal = skb;

  reduce1_k<<<RBLK, 256, 0, stream>>>(logit, vcl, Sfinal, partials);
  finalize2_k<<<1, 512, 0, stream>>>(partials, out);
}